// Round 1
// baseline (784.056 us; speedup 1.0000x reference)
//
#include <hip/hip_runtime.h>

typedef __bf16 bf16x8 __attribute__((ext_vector_type(8)));
typedef float  f32x4  __attribute__((ext_vector_type(4)));

#define GAS(p) ((const __attribute__((address_space(1))) void*)(p))
#define LAS(p) ((__attribute__((address_space(3))) void*)(p))

__device__ __forceinline__ float gelu_exact(float x) {
    return 0.5f * x * (1.f + erff(x * 0.70710678118654752440f));
}

// ---------------------------------------------------------------------------
// Stage 1: per-point features. One wave per point, 4 points per 256-thr block.
// Writes G row (160 bf16): [0:40)=fourier feat, [40:148)=gelu patch-MLP hidden,
// [148:160)=0 pad. Also writes t indices (3 ints per point).
// ---------------------------------------------------------------------------
__global__ __launch_bounds__(256) void stage1_kernel(
    const float* __restrict__ query, const float* __restrict__ images,
    const float* __restrict__ pm_w1, const float* __restrict__ pm_b1,
    __bf16* __restrict__ G, int* __restrict__ tbuf)
{
    __shared__ float patch[4][28];
    const int wave = threadIdx.x >> 6, lane = threadIdx.x & 63;
    const int p = blockIdx.x * 4 + wave;
    const float* q = query + (size_t)p * 5;
    float u = fminf(fmaxf(q[0], 0.f), 1.f);
    float v = fminf(fmaxf(q[1], 0.f), 1.f);
    int ts = min(max((int)rintf(q[2]), 0), 47);
    int tt = min(max((int)rintf(q[3]), 0), 47);
    int tc = min(max((int)rintf(q[4]), 0), 47);
    const int b = p >> 13;  // N = 8192 points per batch
    if (lane < 27) {
        int c = lane / 9, rem = lane % 9, dy = rem / 3, dx = rem % 3;
        int x = (int)rintf(u * 255.f), y = (int)rintf(v * 255.f);
        int xx = min(max(x + dx - 1, 0), 255);
        int yy = min(max(y + dy - 1, 0), 255);
        // images layout (B, C, T, H, W); transposed access [b][t][c][y][x]
        size_t idx = ((size_t)((b * 3 + c) * 48 + ts) << 16) + ((size_t)yy << 8) + (size_t)xx;
        patch[wave][lane] = images[idx];
    }
    if (lane < 40) {
        int i = lane % 10;
        float base = (lane < 20) ? u : v;
        float ph = 6.28318530717958647693f * base * exp2f((float)i);
        float val = ((lane / 10) & 1) ? cosf(ph) : sinf(ph);
        G[(size_t)p * 160 + lane] = (__bf16)val;
    }
    if (lane >= 52) G[(size_t)p * 160 + 96 + lane] = (__bf16)0.f;  // cols 148..159
    if (lane < 3) tbuf[p * 3 + lane] = (lane == 0) ? ts : (lane == 1) ? tt : tc;
    __syncthreads();
    for (int j = lane; j < 108; j += 64) {
        float acc = pm_b1[j];
        #pragma unroll
        for (int i2 = 0; i2 < 27; i2++)
            acc = fmaf(patch[wave][i2], pm_w1[i2 * 108 + j], acc);
        G[(size_t)p * 160 + 40 + j] = (__bf16)gelu_exact(acc);
    }
}

// ---------------------------------------------------------------------------
// Prepack: transpose f32 (R x C) -> bf16 (C x R)
// ---------------------------------------------------------------------------
__global__ __launch_bounds__(256) void transpose_to_bf16(
    const float* __restrict__ src, __bf16* __restrict__ dst, int R, int C)
{
    __shared__ float t[32][33];
    const int c0 = blockIdx.x * 32, r0 = blockIdx.y * 32;
    const int tx = threadIdx.x & 31, ty = threadIdx.x >> 5;  // ty 0..7
    #pragma unroll
    for (int i = 0; i < 32; i += 8)
        t[ty + i][tx] = src[(size_t)(r0 + ty + i) * C + (c0 + tx)];
    __syncthreads();
    #pragma unroll
    for (int i = 0; i < 32; i += 8)
        dst[(size_t)(c0 + ty + i) * R + (r0 + tx)] = (__bf16)t[tx][ty + i];
}

// Prepack: Wcat_t (768 x 160) bf16: row n, k<40 -> uv_w[k][n]; k<148 -> pm_w2[k-40][n]; else 0
__global__ __launch_bounds__(256) void build_wcat(
    const float* __restrict__ uv_w, const float* __restrict__ pm_w2, __bf16* __restrict__ Wt)
{
    int idx = blockIdx.x * 256 + threadIdx.x;  // < 768*160
    int n = idx / 160, k = idx % 160;
    float v = 0.f;
    if (k < 40) v = uv_w[k * 768 + n];
    else if (k < 148) v = pm_w2[(k - 40) * 768 + n];
    Wt[idx] = (__bf16)v;
}

// ---------------------------------------------------------------------------
// m97-style bf16 MFMA GEMM: C(MxN) = A(MxK) @ Bt(NxK)^T, K % 32 == 0,
// M,N % 128 == 0. 256 threads, 4 waves in 2x2, each wave 4x4 16x16x32 tiles.
// EPI 0: + uv_b + pm_b2 + 3 embed rows -> bf16
// EPI 1: + bias, exact gelu -> bf16
// EPI 2: + bias -> f32
// ---------------------------------------------------------------------------
enum { EPI_X = 0, EPI_GELU = 1, EPI_OUT = 2 };

template <int EPI, typename OutT>
__global__ __launch_bounds__(256) void gemm_bt(
    const __bf16* __restrict__ A, const __bf16* __restrict__ Bt, int K,
    const float* __restrict__ bias, const float* __restrict__ bias2,
    const int* __restrict__ tbuf,
    const float* __restrict__ e0, const float* __restrict__ e1, const float* __restrict__ e2,
    OutT* __restrict__ Cmat, int N)
{
    __shared__ __attribute__((aligned(16))) __bf16 As[128 * 32];
    __shared__ __attribute__((aligned(16))) __bf16 Bs[128 * 32];
    const int tid = threadIdx.x;
    const int wave = tid >> 6, lane = tid & 63;
    const int wr = wave >> 1, wc = wave & 1;
    const int quad = lane >> 4, l15 = lane & 15;
    const long m0 = (long)blockIdx.y * 128;
    const long n0 = (long)blockIdx.x * 128;

    f32x4 acc[4][4];
    #pragma unroll
    for (int i = 0; i < 4; i++)
        #pragma unroll
        for (int j = 0; j < 4; j++)
            #pragma unroll
            for (int r = 0; r < 4; r++)
                acc[i][j][r] = 0.f;

    // staging: 512 16B-chunks per tile; chunk = row*4 + kchunk; per-wave-uniform
    // LDS base + lane*16 (global_load_lds constraint).
    const int ch0 = wave * 64 + lane;
    const int ch1 = (wave + 4) * 64 + lane;
    const __bf16* A0 = A + (m0 + (ch0 >> 2)) * (long)K + (ch0 & 3) * 8;
    const __bf16* A1 = A + (m0 + (ch1 >> 2)) * (long)K + (ch1 & 3) * 8;
    const __bf16* B0 = Bt + (n0 + (ch0 >> 2)) * (long)K + (ch0 & 3) * 8;
    const __bf16* B1 = Bt + (n0 + (ch1 >> 2)) * (long)K + (ch1 & 3) * 8;
    __bf16* lA0 = As + wave * 512;        // bytes: wave*1024
    __bf16* lA1 = As + (wave + 4) * 512;
    __bf16* lB0 = Bs + wave * 512;
    __bf16* lB1 = Bs + (wave + 4) * 512;

    for (int kt = 0; kt < K; kt += 32) {
        __builtin_amdgcn_global_load_lds(GAS(A0 + kt), LAS(lA0), 16, 0, 0);
        __builtin_amdgcn_global_load_lds(GAS(A1 + kt), LAS(lA1), 16, 0, 0);
        __builtin_amdgcn_global_load_lds(GAS(B0 + kt), LAS(lB0), 16, 0, 0);
        __builtin_amdgcn_global_load_lds(GAS(B1 + kt), LAS(lB1), 16, 0, 0);
        __syncthreads();
        bf16x8 af[4], bfr[4];
        #pragma unroll
        for (int i = 0; i < 4; i++)
            af[i] = *(const bf16x8*)&As[(wr * 64 + i * 16 + l15) * 32 + quad * 8];
        #pragma unroll
        for (int j = 0; j < 4; j++)
            bfr[j] = *(const bf16x8*)&Bs[(wc * 64 + j * 16 + l15) * 32 + quad * 8];
        #pragma unroll
        for (int i = 0; i < 4; i++)
            #pragma unroll
            for (int j = 0; j < 4; j++)
                acc[i][j] = __builtin_amdgcn_mfma_f32_16x16x32_bf16(af[i], bfr[j], acc[i][j], 0, 0, 0);
        __syncthreads();
    }

    // C/D layout: col = lane&15, row = quad*4 + reg (measured m89/m91)
    #pragma unroll
    for (int i = 0; i < 4; i++) {
        #pragma unroll
        for (int r = 0; r < 4; r++) {
            long row = m0 + wr * 64 + i * 16 + quad * 4 + r;
            int t0 = 0, t1 = 0, t2 = 0;
            if constexpr (EPI == EPI_X) {
                t0 = tbuf[row * 3 + 0];
                t1 = tbuf[row * 3 + 1];
                t2 = tbuf[row * 3 + 2];
            }
            #pragma unroll
            for (int j = 0; j < 4; j++) {
                long col = n0 + wc * 64 + j * 16 + l15;
                float val = acc[i][j][r];
                if constexpr (EPI == EPI_X) {
                    val += bias[col] + bias2[col];
                    val += e0[t0 * 768 + col] + e1[t1 * 768 + col] + e2[t2 * 768 + col];
                    Cmat[row * (long)N + col] = (OutT)val;
                } else if constexpr (EPI == EPI_GELU) {
                    val += bias[col];
                    Cmat[row * (long)N + col] = (OutT)gelu_exact(val);
                } else {
                    val += bias[col];
                    Cmat[row * (long)N + col] = (OutT)val;
                }
            }
        }
    }
}

// ---------------------------------------------------------------------------
// workspace layout (bytes, all 256-aligned)
// ---------------------------------------------------------------------------
static constexpr size_t OFF_G  = 0;          // 32768*160*2  = 10485760
static constexpr size_t OFF_T  = 10485760;   // 32768*3*4    = 393216
static constexpr size_t OFF_WC = 10878976;   // 768*160*2    = 245760
static constexpr size_t OFF_W1 = 11124736;   // 3072*768*2   = 4718592
static constexpr size_t OFF_W2 = 15843328;   // 768*3072*2   = 4718592
static constexpr size_t OFF_X  = 20561920;   // 32768*768*2  = 50331648
static constexpr size_t OFF_H2 = 70893568;   // Mc*3072*2

extern "C" void kernel_launch(void* const* d_in, const int* in_sizes, int n_in,
                              void* d_out, int out_size, void* d_ws, size_t ws_size,
                              hipStream_t stream)
{
    const float* query  = (const float*)d_in[0];
    const float* images = (const float*)d_in[1];
    const float* uv_w   = (const float*)d_in[2];
    const float* uv_b   = (const float*)d_in[3];
    const float* e_src  = (const float*)d_in[4];
    const float* e_tgt  = (const float*)d_in[5];
    const float* e_cam  = (const float*)d_in[6];
    const float* pm_w1  = (const float*)d_in[7];
    const float* pm_b1  = (const float*)d_in[8];
    const float* pm_w2  = (const float*)d_in[9];
    const float* pm_b2  = (const float*)d_in[10];
    const float* om_w1  = (const float*)d_in[11];
    const float* om_b1  = (const float*)d_in[12];
    const float* om_w2  = (const float*)d_in[13];
    const float* om_b2  = (const float*)d_in[14];
    float* out = (float*)d_out;
    char* ws = (char*)d_ws;

    __bf16* G    = (__bf16*)(ws + OFF_G);
    int*    tb   = (int*)(ws + OFF_T);
    __bf16* Wcat = (__bf16*)(ws + OFF_WC);
    __bf16* W1t  = (__bf16*)(ws + OFF_W1);
    __bf16* W2t  = (__bf16*)(ws + OFF_W2);
    __bf16* X    = (__bf16*)(ws + OFF_X);
    __bf16* H2   = (__bf16*)(ws + OFF_H2);

    // stage 1 + weight prepacks (independent)
    stage1_kernel<<<8192, 256, 0, stream>>>(query, images, pm_w1, pm_b1, G, tb);
    transpose_to_bf16<<<dim3(3072 / 32, 768 / 32), 256, 0, stream>>>(om_w1, W1t, 768, 3072);
    transpose_to_bf16<<<dim3(768 / 32, 3072 / 32), 256, 0, stream>>>(om_w2, W2t, 3072, 768);
    build_wcat<<<480, 256, 0, stream>>>(uv_w, pm_w2, Wcat);

    // X = G @ Wcat^T + uv_b + pm_b2 + embeds   (M=32768, N=768, K=160)
    gemm_bt<EPI_X, __bf16><<<dim3(768 / 128, 32768 / 128), 256, 0, stream>>>(
        G, Wcat, 160, uv_b, pm_b2, tb, e_src, e_tgt, e_cam, X, 768);

    // choose largest hidden-chunk that fits ws
    long Mc = 1024;
    for (long cand = 32768; cand >= 1024; cand >>= 1)
        if (OFF_H2 + (size_t)cand * 3072 * 2 <= ws_size) { Mc = cand; break; }

    for (long m = 0; m < 32768; m += Mc) {
        // H2 = gelu(X @ om_w1 + b1)   (Mc x 3072, K=768)
        gemm_bt<EPI_GELU, __bf16><<<dim3(3072 / 128, Mc / 128), 256, 0, stream>>>(
            X + m * 768, W1t, 768, om_b1, nullptr, nullptr, nullptr, nullptr, nullptr, H2, 3072);
        // out = H2 @ om_w2 + b2       (Mc x 768, K=3072)
        gemm_bt<EPI_OUT, float><<<dim3(768 / 128, Mc / 128), 256, 0, stream>>>(
            H2, W2t, 3072, om_b2, nullptr, nullptr, nullptr, nullptr, nullptr, out + m * 768, 768);
    }
}

// Round 2
// 705.485 us; speedup vs baseline: 1.1114x; 1.1114x over previous
//
#include <hip/hip_runtime.h>

typedef __bf16 bf16x8 __attribute__((ext_vector_type(8)));
typedef float  f32x4  __attribute__((ext_vector_type(4)));

#define GAS(p) ((const __attribute__((address_space(1))) void*)(p))
#define LAS(p) ((__attribute__((address_space(3))) void*)(p))

__device__ __forceinline__ float gelu_exact(float x) {
    return 0.5f * x * (1.f + erff(x * 0.70710678118654752440f));
}

// ---------------------------------------------------------------------------
// Stage 1: per-point features. One wave per point, 4 points per 256-thr block.
// G row (192 bf16): [0:40)=fourier, [40:148)=gelu patch-MLP hidden, [148:192)=0.
// ---------------------------------------------------------------------------
__global__ __launch_bounds__(256) void stage1_kernel(
    const float* __restrict__ query, const float* __restrict__ images,
    const float* __restrict__ pm_w1, const float* __restrict__ pm_b1,
    __bf16* __restrict__ G, int* __restrict__ tbuf)
{
    __shared__ float patch[4][28];
    const int wave = threadIdx.x >> 6, lane = threadIdx.x & 63;
    const int p = blockIdx.x * 4 + wave;
    const float* q = query + (size_t)p * 5;
    float u = fminf(fmaxf(q[0], 0.f), 1.f);
    float v = fminf(fmaxf(q[1], 0.f), 1.f);
    int ts = min(max((int)rintf(q[2]), 0), 47);
    int tt = min(max((int)rintf(q[3]), 0), 47);
    int tc = min(max((int)rintf(q[4]), 0), 47);
    const int b = p >> 13;  // N = 8192 points per batch
    if (lane < 27) {
        int c = lane / 9, rem = lane % 9, dy = rem / 3, dx = rem % 3;
        int x = (int)rintf(u * 255.f), y = (int)rintf(v * 255.f);
        int xx = min(max(x + dx - 1, 0), 255);
        int yy = min(max(y + dy - 1, 0), 255);
        size_t idx = ((size_t)((b * 3 + c) * 48 + ts) << 16) + ((size_t)yy << 8) + (size_t)xx;
        patch[wave][lane] = images[idx];
    }
    if (lane < 40) {
        int i = lane % 10;
        float base = (lane < 20) ? u : v;
        float ph = 6.28318530717958647693f * base * exp2f((float)i);
        float val = ((lane / 10) & 1) ? cosf(ph) : sinf(ph);
        G[(size_t)p * 192 + lane] = (__bf16)val;
    }
    for (int j = 148 + lane; j < 192; j += 64) G[(size_t)p * 192 + j] = (__bf16)0.f;
    if (lane < 3) tbuf[p * 3 + lane] = (lane == 0) ? ts : (lane == 1) ? tt : tc;
    __syncthreads();
    for (int j = lane; j < 108; j += 64) {
        float acc = pm_b1[j];
        #pragma unroll
        for (int i2 = 0; i2 < 27; i2++)
            acc = fmaf(patch[wave][i2], pm_w1[i2 * 108 + j], acc);
        G[(size_t)p * 192 + 40 + j] = (__bf16)gelu_exact(acc);
    }
}

// ---------------------------------------------------------------------------
// Prepack: transpose f32 (R x C) -> bf16 (C x R)
// ---------------------------------------------------------------------------
__global__ __launch_bounds__(256) void transpose_to_bf16(
    const float* __restrict__ src, __bf16* __restrict__ dst, int R, int C)
{
    __shared__ float t[32][33];
    const int c0 = blockIdx.x * 32, r0 = blockIdx.y * 32;
    const int tx = threadIdx.x & 31, ty = threadIdx.x >> 5;
    #pragma unroll
    for (int i = 0; i < 32; i += 8)
        t[ty + i][tx] = src[(size_t)(r0 + ty + i) * C + (c0 + tx)];
    __syncthreads();
    #pragma unroll
    for (int i = 0; i < 32; i += 8)
        dst[(size_t)(c0 + ty + i) * R + (r0 + tx)] = (__bf16)t[tx][ty + i];
}

// Wcat_t (768 x 192) bf16: row n, k<40 -> uv_w[k][n]; k<148 -> pm_w2[k-40][n]; else 0
__global__ __launch_bounds__(256) void build_wcat(
    const float* __restrict__ uv_w, const float* __restrict__ pm_w2, __bf16* __restrict__ Wt)
{
    int idx = blockIdx.x * 256 + threadIdx.x;  // < 768*192
    int n = idx / 192, k = idx % 192;
    float v = 0.f;
    if (k < 40) v = uv_w[k * 768 + n];
    else if (k < 148) v = pm_w2[(k - 40) * 768 + n];
    Wt[idx] = (__bf16)v;
}

// ---------------------------------------------------------------------------
// bf16 MFMA GEMM: C(MxN) = A(MxK) @ Bt(NxK)^T, K%64==0, M%1024==0(8 m-tiles),
// N%128==0. 256 threads, 4 waves 2x2, wave = 4x4 16x16x32 tiles. BK=64,
// XOR-swizzled LDS (conflict-free ds_read_b128), XCD-aware flat-grid swizzle:
// consecutive ids vary m (8) before n so same-m blocks sit 8 apart -> same XCD
// -> A-panel L2 reuse.
// ---------------------------------------------------------------------------
enum { EPI_X = 0, EPI_GELU = 1, EPI_OUT = 2 };

template <int EPI, typename OutT>
__global__ __launch_bounds__(256) void gemm_bt(
    const __bf16* __restrict__ A, const __bf16* __restrict__ Bt, int K,
    const float* __restrict__ bias, const float* __restrict__ bias2,
    const int* __restrict__ tbuf,
    const float* __restrict__ e0, const float* __restrict__ e1, const float* __restrict__ e2,
    OutT* __restrict__ Cmat, int N)
{
    __shared__ __attribute__((aligned(16))) __bf16 As[128 * 64];
    __shared__ __attribute__((aligned(16))) __bf16 Bs[128 * 64];
    const int tid = threadIdx.x;
    const int wave = tid >> 6, lane = tid & 63;
    const int wr = wave >> 1, wc = wave & 1;
    const int quad = lane >> 4, l15 = lane & 15;
    const int sw = l15 & 7;

    // flat-grid swizzle: super-tile of 8 m-tiles x all n-tiles
    const int ntiles = N >> 7;
    const int per_super = ntiles << 3;
    const int id = blockIdx.x;
    const int sup = id / per_super, rem = id - sup * per_super;
    const long m0 = (long)(sup * 8 + (rem & 7)) << 7;
    const long n0 = (long)(rem >> 3) << 7;

    f32x4 acc[4][4];
    #pragma unroll
    for (int i = 0; i < 4; i++)
        #pragma unroll
        for (int j = 0; j < 4; j++)
            #pragma unroll
            for (int r = 0; r < 4; r++)
                acc[i][j][r] = 0.f;

    // Staging: 1024 16B-chunks per matrix per iter (128 rows x 8 chunks).
    // LDS slot (row,s) holds global chunk (row, s ^ (row&7))  [XOR swizzle].
    const __bf16* pa[4]; const __bf16* pb[4];
    __bf16* la[4]; __bf16* lb[4];
    #pragma unroll
    for (int t = 0; t < 4; t++) {
        int c = (t * 4 + wave) * 64 + lane;
        int row = c >> 3, s = c & 7, g = s ^ (row & 7);
        pa[t] = A  + (m0 + row) * (long)K + g * 8;
        pb[t] = Bt + (n0 + row) * (long)K + g * 8;
        la[t] = As + (t * 4 + wave) * 512;
        lb[t] = Bs + (t * 4 + wave) * 512;
    }

    for (int kt = 0; kt < K; kt += 64) {
        #pragma unroll
        for (int t = 0; t < 4; t++) {
            __builtin_amdgcn_global_load_lds(GAS(pa[t] + kt), LAS(la[t]), 16, 0, 0);
            __builtin_amdgcn_global_load_lds(GAS(pb[t] + kt), LAS(lb[t]), 16, 0, 0);
        }
        __syncthreads();
        #pragma unroll
        for (int h = 0; h < 2; h++) {
            const int slot = ((h * 4 + quad) ^ sw) * 8;
            bf16x8 af[4], bfv[4];
            #pragma unroll
            for (int i = 0; i < 4; i++)
                af[i] = *(const bf16x8*)&As[(wr * 64 + i * 16 + l15) * 64 + slot];
            #pragma unroll
            for (int j = 0; j < 4; j++)
                bfv[j] = *(const bf16x8*)&Bs[(wc * 64 + j * 16 + l15) * 64 + slot];
            #pragma unroll
            for (int i = 0; i < 4; i++)
                #pragma unroll
                for (int j = 0; j < 4; j++)
                    acc[i][j] = __builtin_amdgcn_mfma_f32_16x16x32_bf16(af[i], bfv[j], acc[i][j], 0, 0, 0);
        }
        __syncthreads();
    }

    // C/D layout: col = lane&15, row = quad*4 + reg (measured m89/m91)
    #pragma unroll
    for (int i = 0; i < 4; i++) {
        #pragma unroll
        for (int r = 0; r < 4; r++) {
            long row = m0 + wr * 64 + i * 16 + quad * 4 + r;
            int t0 = 0, t1 = 0, t2 = 0;
            if constexpr (EPI == EPI_X) {
                t0 = tbuf[row * 3 + 0];
                t1 = tbuf[row * 3 + 1];
                t2 = tbuf[row * 3 + 2];
            }
            #pragma unroll
            for (int j = 0; j < 4; j++) {
                long col = n0 + wc * 64 + j * 16 + l15;
                float val = acc[i][j][r];
                if constexpr (EPI == EPI_X) {
                    val += bias[col] + bias2[col];
                    val += e0[t0 * 768 + col] + e1[t1 * 768 + col] + e2[t2 * 768 + col];
                    Cmat[row * (long)N + col] = (OutT)val;
                } else if constexpr (EPI == EPI_GELU) {
                    val += bias[col];
                    Cmat[row * (long)N + col] = (OutT)gelu_exact(val);
                } else {
                    val += bias[col];
                    Cmat[row * (long)N + col] = (OutT)val;
                }
            }
        }
    }
}

// ---------------------------------------------------------------------------
// workspace layout (bytes, all 256-aligned)
// ---------------------------------------------------------------------------
static constexpr size_t OFF_G  = 0;          // 32768*192*2  = 12582912
static constexpr size_t OFF_T  = 12582912;   // 32768*3*4    = 393216
static constexpr size_t OFF_WC = 12976128;   // 768*192*2    = 294912
static constexpr size_t OFF_W1 = 13271040;   // 3072*768*2   = 4718592
static constexpr size_t OFF_W2 = 17989632;   // 768*3072*2   = 4718592
static constexpr size_t OFF_X  = 22708224;   // 32768*768*2  = 50331648
static constexpr size_t OFF_H2 = 73039872;   // Mc*3072*2

extern "C" void kernel_launch(void* const* d_in, const int* in_sizes, int n_in,
                              void* d_out, int out_size, void* d_ws, size_t ws_size,
                              hipStream_t stream)
{
    const float* query  = (const float*)d_in[0];
    const float* images = (const float*)d_in[1];
    const float* uv_w   = (const float*)d_in[2];
    const float* uv_b   = (const float*)d_in[3];
    const float* e_src  = (const float*)d_in[4];
    const float* e_tgt  = (const float*)d_in[5];
    const float* e_cam  = (const float*)d_in[6];
    const float* pm_w1  = (const float*)d_in[7];
    const float* pm_b1  = (const float*)d_in[8];
    const float* pm_w2  = (const float*)d_in[9];
    const float* pm_b2  = (const float*)d_in[10];
    const float* om_w1  = (const float*)d_in[11];
    const float* om_b1  = (const float*)d_in[12];
    const float* om_w2  = (const float*)d_in[13];
    const float* om_b2  = (const float*)d_in[14];
    float* out = (float*)d_out;
    char* ws = (char*)d_ws;

    __bf16* G    = (__bf16*)(ws + OFF_G);
    int*    tb   = (int*)(ws + OFF_T);
    __bf16* Wcat = (__bf16*)(ws + OFF_WC);
    __bf16* W1t  = (__bf16*)(ws + OFF_W1);
    __bf16* W2t  = (__bf16*)(ws + OFF_W2);
    __bf16* X    = (__bf16*)(ws + OFF_X);
    __bf16* H2   = (__bf16*)(ws + OFF_H2);

    stage1_kernel<<<8192, 256, 0, stream>>>(query, images, pm_w1, pm_b1, G, tb);
    transpose_to_bf16<<<dim3(3072 / 32, 768 / 32), 256, 0, stream>>>(om_w1, W1t, 768, 3072);
    transpose_to_bf16<<<dim3(768 / 32, 3072 / 32), 256, 0, stream>>>(om_w2, W2t, 3072, 768);
    build_wcat<<<576, 256, 0, stream>>>(uv_w, pm_w2, Wcat);

    // X = G @ Wcat^T + uv_b + pm_b2 + embeds   (M=32768, N=768, K=192)
    gemm_bt<EPI_X, __bf16><<<256 * 6, 256, 0, stream>>>(
        G, Wcat, 192, uv_b, pm_b2, tb, e_src, e_tgt, e_cam, X, 768);

    long Mc = 1024;
    for (long cand = 32768; cand >= 1024; cand >>= 1)
        if (OFF_H2 + (size_t)cand * 3072 * 2 <= ws_size) { Mc = cand; break; }

    for (long m = 0; m < 32768; m += Mc) {
        gemm_bt<EPI_GELU, __bf16><<<(Mc / 128) * 24, 256, 0, stream>>>(
            X + m * 768, W1t, 768, om_b1, nullptr, nullptr, nullptr, nullptr, nullptr, H2, 3072);
        gemm_bt<EPI_OUT, float><<<(Mc / 128) * 6, 256, 0, stream>>>(
            H2, W2t, 3072, om_b2, nullptr, nullptr, nullptr, nullptr, nullptr, out + m * 768, 768);
    }
}